// Round 3
// baseline (5737.131 us; speedup 1.0000x reference)
//
#include <hip/hip_runtime.h>
#include <math.h>

#define NGROUP 4
#define BATCH  4096
#define TSTEPS 128

// ---------------- workspace layout (float offsets) ----------------
#define WI0T_OFF 0               // 4*64*4*48 = 49152 : Wi0t[g][u][gate][k]
#define WH0T_OFF 49152           // 4*64*4*64 = 65536 : Wh0t[g][u][gate][k]
#define B0T_OFF  114688          // 4*64*4    = 1024  : b0t[g][u][gate]
#define WE1T_OFF 115712          // 48*19     = 912   : We1t[u][k]
#define WE2T_OFF 116624          // 48*48     = 2304  : We2t[u][k]
#define WI1T_OFF 118928          // 4*16*64   = 4096  : Wi1t[g][q][k]
#define WH1T_OFF 123024          // 4*16*4    = 256   : Wh1t[g][q][j]
#define KAL_OFF  123280          // 4*128*48  = 24576 : per (g,t): K[24],Sinv[16],logdet
#define LL_OFF   147856          // 4*128*4096 = 2097152
#define XN_OFF   2245008         // 4*128*4096*6 = 12582912
// end = 14,827,920 floats = 59.31 MB (same budget as R1 which fit)

__device__ __forceinline__ float fast_sig(float x) {
    return __builtin_amdgcn_rcpf(1.0f + __expf(-x));
}
__device__ __forceinline__ float fast_tanh(float x) {
    float ax = fabsf(x);
    float t  = __expf(-2.0f * ax);
    float r  = (1.0f - t) * __builtin_amdgcn_rcpf(1.0f + t);
    return copysignf(r, x);
}

// ============ prep 1: transpose weights into unit-major layouts ============
__global__ void nkf_prep_tr(const float* __restrict__ Wi0, const float* __restrict__ Wh0,
                            const float* __restrict__ b0,  const float* __restrict__ We1,
                            const float* __restrict__ We2, const float* __restrict__ Wi1,
                            const float* __restrict__ Wh1, float* __restrict__ ws) {
    int i = blockIdx.x * 256 + threadIdx.x;
    if (i < 49152) {                       // Wi0t[g][u][q][k48] <- Wi0[g][k][q*64+u]
        int g = i / 12288, r = i % 12288, u = r / 192, r2 = r % 192, q = r2 / 48, k = r2 % 48;
        ws[WI0T_OFF + i] = Wi0[g * 12288 + k * 256 + q * 64 + u];
    } else if (i < 114688) {               // Wh0t[g][u][q][k64]
        int j = i - 49152;
        int g = j / 16384, r = j % 16384, u = r / 256, r2 = r % 256, q = r2 / 64, k = r2 % 64;
        ws[WH0T_OFF + j] = Wh0[g * 16384 + k * 256 + q * 64 + u];
    } else if (i < 115712) {               // b0t[g][u][q]
        int j = i - 114688;
        int g = j / 256, r = j % 256, u = r / 4, q = r % 4;
        ws[B0T_OFF + j] = b0[g * 256 + q * 64 + u];
    } else if (i < 116624) {               // We1t[u][k19]
        int j = i - 115712; int u = j / 19, k = j % 19;
        ws[WE1T_OFF + j] = We1[k * 48 + u];
    } else if (i < 118928) {               // We2t[u][k48]
        int j = i - 116624; int u = j / 48, k = j % 48;
        ws[WE2T_OFF + j] = We2[k * 48 + u];
    } else if (i < 123024) {               // Wi1t[g][q][k64]
        int j = i - 118928; int g = j / 1024, r = j % 1024, q = r / 64, k = r % 64;
        ws[WI1T_OFF + j] = Wi1[g * 1024 + k * 16 + q];
    } else if (i < 123280) {               // Wh1t[g][q][j4]
        int j = i - 123024; int g = j / 64, r = j % 64, q = r / 4, jj = r % 4;
        ws[WH1T_OFF + j] = Wh1[g * 64 + jj * 16 + q];
    }
}

// ============ prep 2: data-independent Kalman gain sequence ============
__global__ void nkf_prep_kal(const float* __restrict__ Q_log, const float* __restrict__ R_log,
                             float* __restrict__ ws) {
    int g = blockIdx.x * blockDim.x + threadIdx.x;
    if (g >= NGROUP) return;
    float Qd[6], Rd[4];
#pragma unroll
    for (int i = 0; i < 6; i++) Qd[i] = expf(Q_log[g * 6 + i]);
#pragma unroll
    for (int i = 0; i < 4; i++) Rd[i] = expf(R_log[i]);
    float P[6][6];
#pragma unroll
    for (int i = 0; i < 6; i++)
#pragma unroll
        for (int j = 0; j < 6; j++) P[i][j] = (i == j) ? 1000.0f : 0.0f;
    float* ko = ws + KAL_OFF + (size_t)g * (TSTEPS * 48);

#pragma unroll 1
    for (int t = 0; t < TSTEPS; t++) {
        float FP[6][6], Pp[6][6];
#pragma unroll
        for (int i = 0; i < 6; i++)
#pragma unroll
            for (int j = 0; j < 6; j++) FP[i][j] = P[i][j] + ((i < 3) ? P[i + 3][j] : 0.0f);
#pragma unroll
        for (int i = 0; i < 6; i++)
#pragma unroll
            for (int j = 0; j < 6; j++) Pp[i][j] = FP[i][j] + ((j < 3) ? FP[i][j + 3] : 0.0f);
#pragma unroll
        for (int i = 0; i < 6; i++) Pp[i][i] += Qd[i];

        float S[4][4];
#pragma unroll
        for (int i = 0; i < 4; i++)
#pragma unroll
            for (int j = 0; j < 4; j++) S[i][j] = Pp[i][j] + ((i == j) ? Rd[i] : 0.0f);

        float L[4][4];
#pragma unroll
        for (int j = 0; j < 4; j++) {
            float d = S[j][j];
            for (int k = 0; k < j; k++) d -= L[j][k] * L[j][k];
            L[j][j] = sqrtf(d);
            float inv = 1.0f / L[j][j];
            for (int i = j + 1; i < 4; i++) {
                float s2 = S[i][j];
                for (int k = 0; k < j; k++) s2 -= L[i][k] * L[j][k];
                L[i][j] = s2 * inv;
            }
        }
        float logdet = 2.0f * (logf(L[0][0]) + logf(L[1][1]) + logf(L[2][2]) + logf(L[3][3]));

        float Li[4][4];
#pragma unroll
        for (int j = 0; j < 4; j++) {
            Li[j][j] = 1.0f / L[j][j];
            for (int i = j + 1; i < 4; i++) {
                float s2 = 0.0f;
                for (int k = j; k < i; k++) s2 += L[i][k] * Li[k][j];
                Li[i][j] = -s2 / L[i][i];
            }
        }
        float Si[4][4];
#pragma unroll
        for (int i = 0; i < 4; i++)
#pragma unroll
            for (int j = 0; j < 4; j++) {
                float s2 = 0.0f;
                for (int k = (i > j ? i : j); k < 4; k++) s2 += Li[k][i] * Li[k][j];
                Si[i][j] = s2;
            }
        float K[6][4];
#pragma unroll
        for (int i = 0; i < 6; i++)
#pragma unroll
            for (int o = 0; o < 4; o++) {
                float s2 = 0.0f;
                for (int m = 0; m < 4; m++) s2 += Pp[i][m] * Si[m][o];
                K[i][o] = s2;
            }
#pragma unroll
        for (int i = 0; i < 6; i++)
#pragma unroll
            for (int o = 0; o < 4; o++) ko[t * 48 + i * 4 + o] = K[i][o];
#pragma unroll
        for (int i = 0; i < 4; i++)
#pragma unroll
            for (int j = 0; j < 4; j++) ko[t * 48 + 24 + i * 4 + j] = Si[i][j];
        ko[t * 48 + 40] = logdet;

        float Pn[6][6];
#pragma unroll
        for (int i = 0; i < 6; i++)
#pragma unroll
            for (int j = 0; j < 6; j++) {
                float s2 = Pp[i][j];
                for (int m = 0; m < 4; m++) s2 -= K[i][m] * Pp[m][j];
                Pn[i][j] = s2;
            }
#pragma unroll
        for (int i = 0; i < 6; i++)
#pragma unroll
            for (int j = 0; j < 6; j++) P[i][j] = Pn[i][j];
    }
}

// ============ main: lane = chain; 8 waves slice output units ============
// block = 512 thr = 8 waves, 64 chains; 256 blocks; all MACs are v_fmac with s_load weights.
__global__ __launch_bounds__(512, 2) void nkf_main(
    const float* __restrict__ z, const float* __restrict__ x0,
    const float* __restrict__ be1, const float* __restrict__ be2,
    const float* __restrict__ b1l, const float* __restrict__ ws,
    float* __restrict__ ll_out, float* __restrict__ xn_out) {
    __shared__ float e1buf[48 * 64];
    __shared__ float e2buf[48 * 64];
    __shared__ float h0buf[64 * 64];
    __shared__ float g1buf[16 * 64];

    const int tid = threadIdx.x;
    const int l   = tid & 63;
    const int wq  = __builtin_amdgcn_readfirstlane(tid >> 6);   // wave id 0..7 (uniform)
    const int g   = blockIdx.x >> 6;
    const int bq  = (blockIdx.x & 63) * 64 + l;                 // chain (batch) index

    // wave-uniform weight slice pointers -> scalar loads
    const float* wi0 = ws + WI0T_OFF + g * 12288 + wq * 1536;   // 8 units * 4 gates * 48
    const float* wh0 = ws + WH0T_OFF + g * 16384 + wq * 2048;   // 8 units * 4 gates * 64
    const float* b0t = ws + B0T_OFF  + g * 256   + wq * 32;     // 8 units * 4
    const float* we1 = ws + WE1T_OFF + wq * 114;                // 6 units * 19
    const float* we2 = ws + WE2T_OFF + wq * 288;                // 6 units * 48
    const float* wi1 = ws + WI1T_OFF + g * 1024  + wq * 128;    // 2 gates * 64
    const float* wh1 = ws + WH1T_OFF + g * 64    + wq * 8;      // 2 gates * 4
    const float* be1w = be1 + wq * 6;
    const float* be2w = be2 + wq * 6;
    const float* b1w  = b1l + g * 16 + wq * 2;
    const float* kal  = ws + KAL_OFF + g * (TSTEPS * 48);

    // per-lane chain state (replicated across waves where needed)
    float x[6], h1[4], c1[4], h0r[64], c0[8], zcur[4];
#pragma unroll
    for (int i = 0; i < 6; i++) x[i] = x0[bq * 6 + i];
#pragma unroll
    for (int i = 0; i < 4; i++) { h1[i] = 0.0f; c1[i] = 0.0f; }
#pragma unroll
    for (int k = 0; k < 64; k++) h0r[k] = 0.0f;
#pragma unroll
    for (int u = 0; u < 8; u++) c0[u] = 0.0f;
    {
        float4 zv = *(const float4*)(z + (size_t)bq * (TSTEPS * 4));
        zcur[0] = zv.x; zcur[1] = zv.y; zcur[2] = zv.z; zcur[3] = zv.w;
    }

    for (int t = 0; t < TSTEPS; ++t) {
        // ---------- feats (per-lane, replicated in all waves) ----------
        float f[19];
        f[0] = zcur[0]; f[1] = zcur[1]; f[2] = zcur[2]; f[3] = zcur[3];
#pragma unroll
        for (int i = 0; i < 6; i++) f[4 + i] = x[i];
        {
            float i0 = zcur[0] - x[0], i1 = zcur[1] - x[1];
            float i2 = zcur[2] - x[2], i3 = zcur[3] - x[3];
            f[10] = i0; f[11] = i1; f[12] = i2; f[13] = i3;
            f[14] = sqrtf(i0 * i0 + i1 * i1 + i2 * i2 + i3 * i3);
            f[15] = sqrtf(x[0] * x[0] + x[1] * x[1] + x[2] * x[2]);
            f[16] = sqrtf(x[3] * x[3] + x[4] * x[4] + x[5] * x[5]);
            f[17] = (float)t * 0.01f;
            f[18] = 1.0f;
        }
        // prefetch next z (used next iteration)
        float4 znv;
        {
            int tn = (t + 1 < TSTEPS) ? t + 1 : t;
            znv = *(const float4*)(z + (size_t)bq * (TSTEPS * 4) + tn * 4);
        }
        // ---------- E1: this wave computes units 6wq..6wq+5 ----------
#pragma unroll
        for (int u = 0; u < 6; u++) {
            float a = be1w[u];
#pragma unroll
            for (int k = 0; k < 19; k++) a += we1[u * 19 + k] * f[k];
            e1buf[(wq * 6 + u) * 64 + l] = fmaxf(a, 0.0f);
        }
        __syncthreads();
        float e1r[48];
#pragma unroll
        for (int k = 0; k < 48; k++) e1r[k] = e1buf[k * 64 + l];
        // ---------- E2: units 6wq..6wq+5 ----------
#pragma unroll
        for (int u = 0; u < 6; u++) {
            float a = be2w[u];
#pragma unroll
            for (int k = 0; k < 48; k++) a += we2[u * 48 + k] * e1r[k];
            e2buf[(wq * 6 + u) * 64 + l] = fmaxf(a, 0.0f);
        }
        __syncthreads();
        float e2r[48];
#pragma unroll
        for (int k = 0; k < 48; k++) e2r[k] = e2buf[k * 64 + l];
        // ---------- LSTM0: units 8wq..8wq+7 ----------
#pragma unroll
        for (int u = 0; u < 8; u++) {
            const float* wp = wi0 + u * 192;
            const float* hp = wh0 + u * 256;
            float ai = b0t[u * 4 + 0], af = b0t[u * 4 + 1];
            float ag = b0t[u * 4 + 2], ao = b0t[u * 4 + 3];
#pragma unroll
            for (int k = 0; k < 48; k++) {
                float e = e2r[k];
                ai += wp[k] * e; af += wp[48 + k] * e;
                ag += wp[96 + k] * e; ao += wp[144 + k] * e;
            }
#pragma unroll
            for (int k = 0; k < 64; k++) {
                float h = h0r[k];
                ai += hp[k] * h; af += hp[64 + k] * h;
                ag += hp[128 + k] * h; ao += hp[192 + k] * h;
            }
            float cn = fast_sig(af) * c0[u] + fast_sig(ai) * fast_tanh(ag);
            c0[u] = cn;
            h0buf[(wq * 8 + u) * 64 + l] = fast_sig(ao) * fast_tanh(cn);
        }
        __syncthreads();
#pragma unroll
        for (int k = 0; k < 64; k++) h0r[k] = h0buf[k * 64 + l];
        // ---------- LSTM1 gates: gates 2wq, 2wq+1 ----------
#pragma unroll
        for (int q2 = 0; q2 < 2; q2++) {
            float a = b1w[q2];
            const float* wp = wi1 + q2 * 64;
#pragma unroll
            for (int k = 0; k < 64; k++) a += wp[k] * h0r[k];
            const float* hp = wh1 + q2 * 4;
#pragma unroll
            for (int j = 0; j < 4; j++) a += hp[j] * h1[j];
            g1buf[(wq * 2 + q2) * 64 + l] = a;
        }
        __syncthreads();
        float g1r[16];
#pragma unroll
        for (int q = 0; q < 16; q++) g1r[q] = g1buf[q * 64 + l];
        // ---------- LSTM1 finish (replicated) ----------
#pragma unroll
        for (int d = 0; d < 4; d++) {
            float cn = fast_sig(g1r[4 + d]) * c1[d] + fast_sig(g1r[d]) * fast_tanh(g1r[8 + d]);
            c1[d] = cn;
            h1[d] = fast_sig(g1r[12 + d]) * fast_tanh(cn);
        }
        // ---------- Kalman update (replicated; kt is uniform -> s_load) ----------
        const float* kt = kal + t * 48;
        float a0 = h1[1], a1 = h1[2], a2 = h1[3];
        float xp0 = x[0] + x[3] + 0.5f * a0;   // DT = 1
        float xp1 = x[1] + x[4] + 0.5f * a1;
        float xp2 = x[2] + x[5] + 0.5f * a2;
        float xp3 = x[3] + a0;
        float xp4 = x[4] + a1;
        float xp5 = x[5] + a2;
        float y0 = zcur[0] - xp0, y1 = zcur[1] - xp1;
        float y2 = zcur[2] - xp2, y3 = zcur[3] - xp3;
        float xn0 = xp0 + kt[0]  * y0 + kt[1]  * y1 + kt[2]  * y2 + kt[3]  * y3;
        float xn1 = xp1 + kt[4]  * y0 + kt[5]  * y1 + kt[6]  * y2 + kt[7]  * y3;
        float xn2 = xp2 + kt[8]  * y0 + kt[9]  * y1 + kt[10] * y2 + kt[11] * y3;
        float xn3 = xp3 + kt[12] * y0 + kt[13] * y1 + kt[14] * y2 + kt[15] * y3;
        float xn4 = xp4 + kt[16] * y0 + kt[17] * y1 + kt[18] * y2 + kt[19] * y3;
        float xn5 = xp5 + kt[20] * y0 + kt[21] * y1 + kt[22] * y2 + kt[23] * y3;
        float sy0 = kt[24] * y0 + kt[25] * y1 + kt[26] * y2 + kt[27] * y3;
        float sy1 = kt[28] * y0 + kt[29] * y1 + kt[30] * y2 + kt[31] * y3;
        float sy2 = kt[32] * y0 + kt[33] * y1 + kt[34] * y2 + kt[35] * y3;
        float sy3 = kt[36] * y0 + kt[37] * y1 + kt[38] * y2 + kt[39] * y3;
        float quad = y0 * sy0 + y1 * sy1 + y2 * sy2 + y3 * sy3;
        float llv  = h1[0] - 0.5f * (quad + kt[40]);
        x[0] = xn0; x[1] = xn1; x[2] = xn2; x[3] = xn3; x[4] = xn4; x[5] = xn5;
        if (wq == 0) {
            size_t base = ((size_t)(g * TSTEPS + t)) * BATCH + bq;
            ll_out[base] = llv;
            float* xo = xn_out + base * 6;
            xo[0] = xn0; xo[1] = xn1; xo[2] = xn2;
            xo[3] = xn3; xo[4] = xn4; xo[5] = xn5;
        }
        zcur[0] = znv.x; zcur[1] = znv.y; zcur[2] = znv.z; zcur[3] = znv.w;
    }
}

// ============ argmax over groups + gather output ============
__global__ void nkf_gather(const float* __restrict__ ws, float* __restrict__ out) {
    int idx = blockIdx.x * 256 + threadIdx.x;   // t*BATCH + b
    if (idx >= TSTEPS * BATCH) return;
    const float* llp = ws + LL_OFF;
    float best = llp[idx];
    int   bg   = 0;
#pragma unroll
    for (int g2 = 1; g2 < 4; g2++) {
        float v = llp[(size_t)g2 * (TSTEPS * BATCH) + idx];
        if (v > best) { best = v; bg = g2; }
    }
    const float* xp = ws + XN_OFF + ((size_t)bg * (TSTEPS * BATCH) + idx) * 6;
    float* o = out + (size_t)idx * 6;
#pragma unroll
    for (int i = 0; i < 6; i++) o[i] = xp[i];
}

extern "C" void kernel_launch(void* const* d_in, const int* in_sizes, int n_in,
                              void* d_out, int out_size, void* d_ws, size_t ws_size,
                              hipStream_t stream) {
    const float* z   = (const float*)d_in[0];
    const float* x0  = (const float*)d_in[1];
    const float* We1 = (const float*)d_in[2];
    const float* be1 = (const float*)d_in[3];
    const float* We2 = (const float*)d_in[4];
    const float* be2 = (const float*)d_in[5];
    const float* Wi0 = (const float*)d_in[6];
    const float* Wh0 = (const float*)d_in[7];
    const float* b0  = (const float*)d_in[8];
    const float* Wi1 = (const float*)d_in[9];
    const float* Wh1 = (const float*)d_in[10];
    const float* b1l = (const float*)d_in[11];
    const float* Ql  = (const float*)d_in[12];
    const float* Rl  = (const float*)d_in[13];
    float* ws  = (float*)d_ws;
    float* out = (float*)d_out;

    nkf_prep_tr<<<(123280 + 255) / 256, 256, 0, stream>>>(Wi0, Wh0, b0, We1, We2, Wi1, Wh1, ws);
    nkf_prep_kal<<<1, 64, 0, stream>>>(Ql, Rl, ws);
    nkf_main<<<256, 512, 0, stream>>>(z, x0, be1, be2, b1l, ws,
                                      ws + LL_OFF, ws + XN_OFF);
    nkf_gather<<<2048, 256, 0, stream>>>(ws, out);
}

// Round 6
// 3389.702 us; speedup vs baseline: 1.6925x; 1.6925x over previous
//
#include <hip/hip_runtime.h>
#include <math.h>

#define NGROUP 4
#define BATCH  4096
#define TSTEPS 128

// ---------------- workspace layout (float offsets) ----------------
#define WI0T_OFF 0               // 4*48*64*4  = 49152  : Wi0t[g][k][u][gate]
#define WH0T_OFF 49152           // 4*64*64*4  = 65536  : Wh0t[g][k][u][gate]
#define B0T_OFF  114688          // 4*64*4     = 1024   : b0t[g][u][gate]
#define KAL_OFF  115712          // 4*128*48   = 24576  : per (g,t): K[24], Sinv[16], logdet
#define LL_OFF   147456          // 4*128*4096 = 2097152
#define XN_OFF   (147456 + 2097152)   // 4*128*4096*6 = 12582912

// ---------------- LDS layout (float offsets) ----------------
#define LWH0   0                 // 16384 : [k64][u64][gate4]
#define LB0    16384             // 256   : [u][gate4]
#define LWE1   16640             // 912   : [k19][u48]
#define LBE1   17552             // 48
#define LWE2   17600             // 2304  : [k48][u48]
#define LBE2   19904             // 48
#define LWI1   19952             // 1024  : [k64][q16]
#define LWH1   20976             // 64    : [j4][q16]
#define LB1    21040             // 16
#define LWAVE  21056             // 16 waves * 656 (bufA 192 | bufB 192 | h0b 256 | h1b 16)
#define SMEM_FLOATS (21056 + 16*656)   // 31552 floats = 126208 bytes

__device__ __forceinline__ float fast_sig(float x) {
    return __builtin_amdgcn_rcpf(1.0f + __expf(-x));
}
__device__ __forceinline__ float fast_tanh(float x) {
    float ax = fabsf(x);
    float t  = __expf(-2.0f * ax);
    float r  = (1.0f - t) * __builtin_amdgcn_rcpf(1.0f + t);
    return copysignf(r, x);
}

// ============ prep 1: transpose LSTM0 weights into [k][u][gate4] ============
__global__ void nkf_prep_tr(const float* __restrict__ Wi0, const float* __restrict__ Wh0,
                            const float* __restrict__ b0, float* __restrict__ ws) {
    int idx = blockIdx.x * 256 + threadIdx.x;
    if (idx < 49152) {
        int g = idx / 12288, r2 = idx % 12288;
        int k = r2 >> 8, u = (r2 & 255) >> 2, s = r2 & 3;
        ws[WI0T_OFF + idx] = Wi0[g * 12288 + k * 256 + s * 64 + u];
    } else if (idx < 49152 + 65536) {
        int j = idx - 49152;
        int g = j / 16384, r2 = j % 16384;
        int k = r2 >> 8, u = (r2 & 255) >> 2, s = r2 & 3;
        ws[WH0T_OFF + j] = Wh0[g * 16384 + k * 256 + s * 64 + u];
    } else if (idx < 49152 + 65536 + 1024) {
        int j = idx - 114688;
        int g = j >> 8, r2 = j & 255;
        int u = r2 >> 2, s = r2 & 3;
        ws[B0T_OFF + j] = b0[g * 256 + s * 64 + u];
    }
}

// ============ prep 2: data-independent Kalman gain sequence ============
__global__ void nkf_prep_kal(const float* __restrict__ Q_log, const float* __restrict__ R_log,
                             float* __restrict__ ws) {
    int g = blockIdx.x * blockDim.x + threadIdx.x;
    if (g >= NGROUP) return;
    float Qd[6], Rd[4];
#pragma unroll
    for (int i = 0; i < 6; i++) Qd[i] = expf(Q_log[g * 6 + i]);
#pragma unroll
    for (int i = 0; i < 4; i++) Rd[i] = expf(R_log[i]);
    float P[6][6];
#pragma unroll
    for (int i = 0; i < 6; i++)
#pragma unroll
        for (int j = 0; j < 6; j++) P[i][j] = (i == j) ? 1000.0f : 0.0f;
    float* ko = ws + KAL_OFF + (size_t)g * (TSTEPS * 48);

#pragma unroll 1
    for (int t = 0; t < TSTEPS; t++) {
        float FP[6][6], Pp[6][6];
#pragma unroll
        for (int i = 0; i < 6; i++)
#pragma unroll
            for (int j = 0; j < 6; j++) FP[i][j] = P[i][j] + ((i < 3) ? P[i + 3][j] : 0.0f);
#pragma unroll
        for (int i = 0; i < 6; i++)
#pragma unroll
            for (int j = 0; j < 6; j++) Pp[i][j] = FP[i][j] + ((j < 3) ? FP[i][j + 3] : 0.0f);
#pragma unroll
        for (int i = 0; i < 6; i++) Pp[i][i] += Qd[i];

        float S[4][4];
#pragma unroll
        for (int i = 0; i < 4; i++)
#pragma unroll
            for (int j = 0; j < 4; j++) S[i][j] = Pp[i][j] + ((i == j) ? Rd[i] : 0.0f);

        float L[4][4];
#pragma unroll
        for (int j = 0; j < 4; j++) {
            float d = S[j][j];
            for (int k = 0; k < j; k++) d -= L[j][k] * L[j][k];
            L[j][j] = sqrtf(d);
            float inv = 1.0f / L[j][j];
            for (int i = j + 1; i < 4; i++) {
                float s2 = S[i][j];
                for (int k = 0; k < j; k++) s2 -= L[i][k] * L[j][k];
                L[i][j] = s2 * inv;
            }
        }
        float logdet = 2.0f * (logf(L[0][0]) + logf(L[1][1]) + logf(L[2][2]) + logf(L[3][3]));

        float Li[4][4];
#pragma unroll
        for (int j = 0; j < 4; j++) {
            Li[j][j] = 1.0f / L[j][j];
            for (int i = j + 1; i < 4; i++) {
                float s2 = 0.0f;
                for (int k = j; k < i; k++) s2 += L[i][k] * Li[k][j];
                Li[i][j] = -s2 / L[i][i];
            }
        }
        float Si[4][4];
#pragma unroll
        for (int i = 0; i < 4; i++)
#pragma unroll
            for (int j = 0; j < 4; j++) {
                float s2 = 0.0f;
                for (int k = (i > j ? i : j); k < 4; k++) s2 += Li[k][i] * Li[k][j];
                Si[i][j] = s2;
            }
        float K[6][4];
#pragma unroll
        for (int i = 0; i < 6; i++)
#pragma unroll
            for (int o = 0; o < 4; o++) {
                float s2 = 0.0f;
                for (int m = 0; m < 4; m++) s2 += Pp[i][m] * Si[m][o];
                K[i][o] = s2;
            }
#pragma unroll
        for (int i = 0; i < 6; i++)
#pragma unroll
            for (int o = 0; o < 4; o++) ko[t * 48 + i * 4 + o] = K[i][o];
#pragma unroll
        for (int i = 0; i < 4; i++)
#pragma unroll
            for (int j = 0; j < 4; j++) ko[t * 48 + 24 + i * 4 + j] = Si[i][j];
        ko[t * 48 + 40] = logdet;

        float Pn[6][6];
#pragma unroll
        for (int i = 0; i < 6; i++)
#pragma unroll
            for (int j = 0; j < 6; j++) {
                float s2 = Pp[i][j];
                for (int m = 0; m < 4; m++) s2 -= K[i][m] * Pp[m][j];
                Pn[i][j] = s2;
            }
#pragma unroll
        for (int i = 0; i < 6; i++)
#pragma unroll
            for (int j = 0; j < 6; j++) P[i][j] = Pn[i][j];
    }
}

// ============ main: lane = unit; 4 chains/wave; 16 waves/block; 4 waves/SIMD ============
__global__ __launch_bounds__(1024, 4) void nkf_main(
    const float* __restrict__ z, const float* __restrict__ x0,
    const float* __restrict__ We1, const float* __restrict__ be1,
    const float* __restrict__ We2, const float* __restrict__ be2,
    const float* __restrict__ Wi1, const float* __restrict__ Wh1,
    const float* __restrict__ b1l, const float* __restrict__ ws,
    float* __restrict__ ll_out, float* __restrict__ xn_out) {
    extern __shared__ float sm[];
    const int tid  = threadIdx.x;
    const int g    = blockIdx.x >> 6;
    const int bblk = blockIdx.x & 63;
    const int w    = tid >> 6;
    const int l    = tid & 63;

    {   // cooperative weight staging
        const float* wh0g = ws + WH0T_OFF + g * 16384;
        for (int i = tid; i < 16384; i += 1024) sm[LWH0 + i] = wh0g[i];
        if (tid < 256) sm[LB0 + tid] = ws[B0T_OFF + g * 256 + tid];
        if (tid < 912) sm[LWE1 + tid] = We1[tid];
        if (tid < 48) sm[LBE1 + tid] = be1[tid];
        for (int i = tid; i < 2304; i += 1024) sm[LWE2 + i] = We2[i];
        if (tid < 48) sm[LBE2 + tid] = be2[tid];
        sm[LWI1 + tid] = Wi1[g * 1024 + tid];
        if (tid < 64) sm[LWH1 + tid] = Wh1[g * 64 + tid];
        if (tid < 16) sm[LB1 + tid] = b1l[g * 16 + tid];
    }

    float* bufA = sm + LWAVE + w * 656;
    float* bufB = bufA + 192;
    float* h0b  = bufB + 192;
    float* h1b  = h0b + 256;
    {
        float4 z4 = {0.0f, 0.0f, 0.0f, 0.0f};
        *(float4*)&h0b[l * 4] = z4;              // h_prev = 0
        if (l < 16) h1b[l] = 0.0f;
    }
    __syncthreads();

    const int c  = l >> 4;          // chain 0..3
    const int r  = l & 15;
    const int bq = bblk * 64 + w * 4 + c;

    float c0v[4];
#pragma unroll
    for (int i = 0; i < 4; i++) c0v[i] = 0.0f;
    float c1u = 0.0f;
    float xr[6] = {0, 0, 0, 0, 0, 0};
    float4 zcur = {0, 0, 0, 0};
    if (r == 0) {
#pragma unroll
        for (int i = 0; i < 6; i++) xr[i] = x0[bq * 6 + i];
        zcur = *(const float4*)(z + (size_t)bq * (TSTEPS * 4));
    }
    const float*  kal  = ws + KAL_OFF + (size_t)g * (TSTEPS * 48);
    const float4* wi0g = (const float4*)(ws + WI0T_OFF) + (size_t)g * 3072;

    for (int t = 0; t < TSTEPS; ++t) {
        // ---- prefetch next z (r==0 lanes) ----
        float4 znv = {0, 0, 0, 0};
        if (r == 0) {
            int tn = (t + 1 < TSTEPS) ? t + 1 : t;
            znv = *(const float4*)(z + ((size_t)bq * TSTEPS + tn) * 4);
        }
        // ---------- feats -> bufA[k][c] (r==0 lanes) ----------
        if (r == 0) {
            bufA[0 * 4 + c] = zcur.x; bufA[1 * 4 + c] = zcur.y;
            bufA[2 * 4 + c] = zcur.z; bufA[3 * 4 + c] = zcur.w;
#pragma unroll
            for (int i = 0; i < 6; i++) bufA[(4 + i) * 4 + c] = xr[i];
            float i0 = zcur.x - xr[0], i1 = zcur.y - xr[1];
            float i2 = zcur.z - xr[2], i3 = zcur.w - xr[3];
            bufA[10 * 4 + c] = i0; bufA[11 * 4 + c] = i1;
            bufA[12 * 4 + c] = i2; bufA[13 * 4 + c] = i3;
            bufA[14 * 4 + c] = sqrtf(i0 * i0 + i1 * i1 + i2 * i2 + i3 * i3);
            bufA[15 * 4 + c] = sqrtf(xr[0] * xr[0] + xr[1] * xr[1] + xr[2] * xr[2]);
            bufA[16 * 4 + c] = sqrtf(xr[3] * xr[3] + xr[4] * xr[4] + xr[5] * xr[5]);
            bufA[17 * 4 + c] = (float)t * 0.01f;
            bufA[18 * 4 + c] = 1.0f;
        }
        asm volatile("" ::: "memory");
        // ---------- E1: lanes 0..47 (lane = unit) -> bufB ----------
        if (l < 48) {
            float a0 = sm[LBE1 + l], a1 = a0, a2 = a0, a3 = a0;
#pragma unroll
            for (int k = 0; k < 19; k++) {
                float  wv = sm[LWE1 + k * 48 + l];
                float4 av = *(const float4*)&bufA[k * 4];
                a0 += wv * av.x; a1 += wv * av.y; a2 += wv * av.z; a3 += wv * av.w;
            }
            float4 o = {fmaxf(a0, 0.0f), fmaxf(a1, 0.0f), fmaxf(a2, 0.0f), fmaxf(a3, 0.0f)};
            *(float4*)&bufB[l * 4] = o;
        }
        asm volatile("" ::: "memory");
        // ---------- E2: lanes 0..47 -> bufA (overwrites feats) ----------
        if (l < 48) {
            float a0 = sm[LBE2 + l], a1 = a0, a2 = a0, a3 = a0;
#pragma unroll 4
            for (int k = 0; k < 48; k++) {
                float  wv = sm[LWE2 + k * 48 + l];
                float4 av = *(const float4*)&bufB[k * 4];
                a0 += wv * av.x; a1 += wv * av.y; a2 += wv * av.z; a3 += wv * av.w;
            }
            float4 o = {fmaxf(a0, 0.0f), fmaxf(a1, 0.0f), fmaxf(a2, 0.0f), fmaxf(a3, 0.0f)};
            *(float4*)&bufA[l * 4] = o;
        }
        asm volatile("" ::: "memory");
        // ---------- LSTM0: lane = unit, 4 chains register-blocked ----------
        float ai[4], af[4], ag[4], ao[4];
        {
            float4 bb = *(const float4*)&sm[LB0 + l * 4];
#pragma unroll
            for (int i = 0; i < 4; i++) { ai[i] = bb.x; af[i] = bb.y; ag[i] = bb.z; ao[i] = bb.w; }
        }
#pragma unroll 4
        for (int k = 0; k < 48; k++) {
            float4 wv = wi0g[k * 64 + l];
            float4 av = *(const float4*)&bufA[k * 4];
            float ev[4] = {av.x, av.y, av.z, av.w};
#pragma unroll
            for (int i = 0; i < 4; i++) {
                ai[i] += wv.x * ev[i]; af[i] += wv.y * ev[i];
                ag[i] += wv.z * ev[i]; ao[i] += wv.w * ev[i];
            }
        }
#pragma unroll 4
        for (int k = 0; k < 64; k++) {
            float4 wv = *(const float4*)&sm[LWH0 + (k * 64 + l) * 4];
            float4 hv = *(const float4*)&h0b[k * 4];
            float hvv[4] = {hv.x, hv.y, hv.z, hv.w};
#pragma unroll
            for (int i = 0; i < 4; i++) {
                ai[i] += wv.x * hvv[i]; af[i] += wv.y * hvv[i];
                ag[i] += wv.z * hvv[i]; ao[i] += wv.w * hvv[i];
            }
        }
        float hnw[4];
#pragma unroll
        for (int i = 0; i < 4; i++) {
            float cn = fast_sig(af[i]) * c0v[i] + fast_sig(ai[i]) * fast_tanh(ag[i]);
            c0v[i] = cn;
            hnw[i] = fast_sig(ao[i]) * fast_tanh(cn);
        }
        asm volatile("" ::: "memory");
        {
            float4 o = {hnw[0], hnw[1], hnw[2], hnw[3]};
            *(float4*)&h0b[l * 4] = o;
        }
        asm volatile("" ::: "memory");
        // ---------- LSTM1: lane = (chain c, gate r) ----------
        float ga = sm[LB1 + r];
#pragma unroll 8
        for (int k = 0; k < 64; k++) {
            ga += sm[LWI1 + k * 16 + r] * h0b[k * 4 + c];
        }
#pragma unroll
        for (int j = 0; j < 4; j++) {
            ga += sm[LWH1 + j * 16 + r] * h1b[j * 4 + c];
        }
        float gf = __shfl_xor(ga, 4, 64);
        float gg = __shfl_xor(ga, 8, 64);
        float go = __shfl_xor(ga, 12, 64);
        asm volatile("" ::: "memory");
        if (r < 4) {
            float cn = fast_sig(gf) * c1u + fast_sig(ga) * fast_tanh(gg);
            c1u = cn;
            h1b[r * 4 + c] = fast_sig(go) * fast_tanh(cn);
        }
        asm volatile("" ::: "memory");
        // ---------- Kalman measurement update (r==0 lanes; kt uniform -> s_load) ----------
        if (r == 0) {
            const float* kt = kal + t * 48;
            float logp = h1b[c];
            float a0v = h1b[4 + c], a1v = h1b[8 + c], a2v = h1b[12 + c];
            float xp0 = xr[0] + xr[3] + 0.5f * a0v;   // DT = 1
            float xp1 = xr[1] + xr[4] + 0.5f * a1v;
            float xp2 = xr[2] + xr[5] + 0.5f * a2v;
            float xp3 = xr[3] + a0v;
            float xp4 = xr[4] + a1v;
            float xp5 = xr[5] + a2v;
            float y0 = zcur.x - xp0, y1 = zcur.y - xp1;
            float y2 = zcur.z - xp2, y3 = zcur.w - xp3;
            float xn0 = xp0 + kt[0]  * y0 + kt[1]  * y1 + kt[2]  * y2 + kt[3]  * y3;
            float xn1 = xp1 + kt[4]  * y0 + kt[5]  * y1 + kt[6]  * y2 + kt[7]  * y3;
            float xn2 = xp2 + kt[8]  * y0 + kt[9]  * y1 + kt[10] * y2 + kt[11] * y3;
            float xn3 = xp3 + kt[12] * y0 + kt[13] * y1 + kt[14] * y2 + kt[15] * y3;
            float xn4 = xp4 + kt[16] * y0 + kt[17] * y1 + kt[18] * y2 + kt[19] * y3;
            float xn5 = xp5 + kt[20] * y0 + kt[21] * y1 + kt[22] * y2 + kt[23] * y3;
            float sy0 = kt[24] * y0 + kt[25] * y1 + kt[26] * y2 + kt[27] * y3;
            float sy1 = kt[28] * y0 + kt[29] * y1 + kt[30] * y2 + kt[31] * y3;
            float sy2 = kt[32] * y0 + kt[33] * y1 + kt[34] * y2 + kt[35] * y3;
            float sy3 = kt[36] * y0 + kt[37] * y1 + kt[38] * y2 + kt[39] * y3;
            float quad = y0 * sy0 + y1 * sy1 + y2 * sy2 + y3 * sy3;
            float llv  = logp - 0.5f * (quad + kt[40]);
            size_t base = ((size_t)(g * TSTEPS + t)) * BATCH + bq;
            ll_out[base] = llv;
            float* xo = xn_out + base * 6;
            xo[0] = xn0; xo[1] = xn1; xo[2] = xn2;
            xo[3] = xn3; xo[4] = xn4; xo[5] = xn5;
            xr[0] = xn0; xr[1] = xn1; xr[2] = xn2;
            xr[3] = xn3; xr[4] = xn4; xr[5] = xn5;
        }
        zcur = znv;
    }
}

// ============ argmax over groups + gather output ============
__global__ void nkf_gather(const float* __restrict__ ws, float* __restrict__ out) {
    int idx = blockIdx.x * 256 + threadIdx.x;   // t*BATCH + b
    if (idx >= TSTEPS * BATCH) return;
    const float* llp = ws + LL_OFF;
    float best = llp[idx];
    int   bg   = 0;
#pragma unroll
    for (int g2 = 1; g2 < 4; g2++) {
        float v = llp[(size_t)g2 * (TSTEPS * BATCH) + idx];
        if (v > best) { best = v; bg = g2; }
    }
    const float* xp = ws + XN_OFF + ((size_t)bg * (TSTEPS * BATCH) + idx) * 6;
    float* o = out + (size_t)idx * 6;
#pragma unroll
    for (int i = 0; i < 6; i++) o[i] = xp[i];
}

extern "C" void kernel_launch(void* const* d_in, const int* in_sizes, int n_in,
                              void* d_out, int out_size, void* d_ws, size_t ws_size,
                              hipStream_t stream) {
    const float* z   = (const float*)d_in[0];
    const float* x0  = (const float*)d_in[1];
    const float* We1 = (const float*)d_in[2];
    const float* be1 = (const float*)d_in[3];
    const float* We2 = (const float*)d_in[4];
    const float* be2 = (const float*)d_in[5];
    const float* Wi0 = (const float*)d_in[6];
    const float* Wh0 = (const float*)d_in[7];
    const float* b0  = (const float*)d_in[8];
    const float* Wi1 = (const float*)d_in[9];
    const float* Wh1 = (const float*)d_in[10];
    const float* b1l = (const float*)d_in[11];
    const float* Ql  = (const float*)d_in[12];
    const float* Rl  = (const float*)d_in[13];
    float* ws  = (float*)d_ws;
    float* out = (float*)d_out;

    (void)hipFuncSetAttribute((const void*)nkf_main,
                              hipFuncAttributeMaxDynamicSharedMemorySize, SMEM_FLOATS * 4);

    nkf_prep_tr<<<(115712 + 255) / 256, 256, 0, stream>>>(Wi0, Wh0, b0, ws);
    nkf_prep_kal<<<1, 64, 0, stream>>>(Ql, Rl, ws);
    nkf_main<<<256, 1024, SMEM_FLOATS * 4, stream>>>(z, x0, We1, be1, We2, be2,
                                                     Wi1, Wh1, b1l, ws,
                                                     ws + LL_OFF, ws + XN_OFF);
    nkf_gather<<<2048, 256, 0, stream>>>(ws, out);
}